// Round 3
// baseline (569.697 us; speedup 1.0000x reference)
//
#include <hip/hip_runtime.h>

#define NTHREADS 512

typedef __attribute__((ext_vector_type(8))) short s16x8;
typedef __attribute__((ext_vector_type(4))) float f32x4;
typedef __attribute__((ext_vector_type(4))) unsigned int u32x4;

__device__ __forceinline__ unsigned short f2bf(float f) {
  unsigned u = __float_as_uint(f);
  u += 0x7fffu + ((u >> 16) & 1u);
  return (unsigned short)(u >> 16);
}
__device__ __forceinline__ float bf2f(unsigned short s) {
  return __uint_as_float(((unsigned)s) << 16);
}
__device__ __forceinline__ float sigm(float x) {
  return __builtin_amdgcn_rcpf(1.0f + __expf(-x));
}
__device__ __forceinline__ float tanh_fast(float x) {
  return 1.0f - 2.0f * __builtin_amdgcn_rcpf(1.0f + __expf(2.0f * x));
}
__device__ __forceinline__ f32x4 mfma_bf16(u32x4 a, u32x4 b, f32x4 c) {
  union { u32x4 u; s16x8 s; } ua, ub;
  ua.u = a; ub.u = b;
  return __builtin_amdgcn_mfma_f32_16x16x32_bf16(ua.s, ub.s, c, 0, 0, 0);
}
// read a bf16 element out of a u32-packed LDS bias array
__device__ __forceinline__ float ldsb(const unsigned* p, int idx) {
  unsigned u = p[idx >> 1];
  return bf2f((unsigned short)((idx & 1) ? (u >> 16) : (u & 0xffffu)));
}

// ---------------- weight pre-pack (UNCHANGED layout) ----------------
// [nb(16)][kb][g(4)][16 n][8 k], bf16.
//   W0p: kb in [0,52)  (k = kb*8: k<160 from W_ih0, else W_hh0)
//   W1p: kb in [0,64)  (k<256 from W_ih1, else W_hh1)
// b0/b1: b_ih+b_hh pre-summed, f32 (packed to bf16 LDS inside lstm_fused).
__global__ void pack_weights(const float* __restrict__ Wih0, const float* __restrict__ Whh0,
                             const float* __restrict__ bih0, const float* __restrict__ bhh0,
                             const float* __restrict__ Wih1, const float* __restrict__ Whh1,
                             const float* __restrict__ bih1, const float* __restrict__ bhh1,
                             unsigned short* __restrict__ W0p, unsigned short* __restrict__ W1p,
                             float* __restrict__ b0, float* __restrict__ b1) {
  int e = blockIdx.x * 256 + threadIdx.x;
  const int N0 = 16 * 52 * 4 * 128;   // 425984
  const int N1 = 16 * 64 * 4 * 128;   // 524288
  if (e < N0) {
    int kk = e & 7, t1 = e >> 3;
    int n = t1 & 15, t2 = t1 >> 4;
    int g = t2 & 3, t3 = t2 >> 2;
    int kb = t3 % 52, nb = t3 / 52;
    int gn = g * 256 + nb * 16 + n, k = kb * 8 + kk;
    float v = (k < 160) ? Wih0[gn * 160 + k] : Whh0[gn * 256 + (k - 160)];
    W0p[e] = f2bf(v);
  } else if (e < N0 + N1) {
    int e2 = e - N0;
    int kk = e2 & 7, t1 = e2 >> 3;
    int n = t1 & 15, t2 = t1 >> 4;
    int g = t2 & 3, t3 = t2 >> 2;
    int kb = t3 & 63, nb = t3 >> 6;
    int gn = g * 256 + nb * 16 + n, k = kb * 8 + kk;
    float v = (k < 256) ? Wih1[gn * 256 + k] : Whh1[gn * 256 + (k - 256)];
    W1p[e2] = f2bf(v);
  } else if (e < N0 + N1 + 1024) {
    int n = e - (N0 + N1);
    b0[n] = bih0[n] + bhh0[n];
  } else if (e < N0 + N1 + 2048) {
    int n = e - (N0 + N1 + 1024);
    b1[n] = bih1[n] + bhh1[n];
  }
}

// ---- rolled K-loop, 32-row A-tiles (N k-groups of 32) ----
// Weights (global, ~250cyc L2 latency) double-buffered via named slots;
// A-frags (LDS ds_read_b128, short) single-buffered — covered by 4-wave TLP.
// Register budget is the constraint: must fit 128 VGPR for 4 waves/SIMD
// (2 independent 512-thread blocks per CU = the occupancy play this round).
__device__ __forceinline__ void ld4(u32x4 d[4], const u32x4* p) {
  d[0] = p[0]; d[1] = p[16]; d[2] = p[32]; d[3] = p[48];
}
__device__ __forceinline__ void mfma8(u32x4 a0, u32x4 a1, const u32x4 b[4],
                                      f32x4 acc[4][2]) {
#pragma unroll
  for (int g = 0; g < 4; g++) {
    acc[g][0] = mfma_bf16(a0, b[g], acc[g][0]);
    acc[g][1] = mfma_bf16(a1, b[g], acc[g][1]);
  }
}
template <int N>
__device__ __forceinline__ void kloop32(const u32x4*& ap, const u32x4*& wp,
                                        f32x4 acc[4][2]) {
  u32x4 b0[4], b1[4];
  ld4(b0, wp); wp += 256;
#pragma unroll 1
  for (int i = 0; i < (N - 1) / 2; i++) {
    ld4(b1, wp); wp += 256;
    { u32x4 a0 = ap[0], a1 = ap[16]; ap += 128; mfma8(a0, a1, b0, acc); }
    ld4(b0, wp); wp += 256;
    { u32x4 a0 = ap[0], a1 = ap[16]; ap += 128; mfma8(a0, a1, b1, acc); }
  }
  if constexpr ((N & 1) == 0) {
    ld4(b1, wp); wp += 256;
    { u32x4 a0 = ap[0], a1 = ap[16]; ap += 128; mfma8(a0, a1, b0, acc); }
    { u32x4 a0 = ap[0], a1 = ap[16]; ap += 128; mfma8(a0, a1, b1, acc); }
  } else {
    { u32x4 a0 = ap[0], a1 = ap[16]; ap += 128; mfma8(a0, a1, b0, acc); }
  }
}

// ---------------- fused 2-layer LSTM + FC ----------------
// Round 10: 512 blocks x 512 threads; block owns 32 batch rows.
// LDS 79872 B -> 2 blocks/CU -> 16 waves/CU = 4 waves/SIMD (was 2).
// The two co-resident blocks have INDEPENDENT barriers: one block's
// barrier/epilogue stall overlaps the other's kloops — this attacks the
// ~50k idle cyc/step that MfmaUtil 39% + 2-wave lockstep showed.
// Cost: weight L2 traffic doubles (9.7 GB, ~4.2 TB/s per XCD at 295 us)
// — that is the known ceiling of this structure.
// VGPR target <=128 (waves_per_eu(4,4)): acc 32 + c 32 + wbuf 32 + a 8
// + addr ~16. Biases bf16-packed in LDS (error ~1e-4 on preacts, safe).
__global__ __attribute__((amdgpu_flat_work_group_size(NTHREADS, NTHREADS),
                          amdgpu_waves_per_eu(4, 4)))
void lstm_fused(const float* __restrict__ x,
                const unsigned short* __restrict__ W0p,
                const unsigned short* __restrict__ W1p,
                const float* __restrict__ b0,
                const float* __restrict__ b1,
                const float* __restrict__ Wfc,
                const float* __restrict__ bfc,
                float* __restrict__ out) {
  __shared__ unsigned int lds_x[2560];    // 10240 B: [20 kblk][32 row][8k bf16]
  __shared__ unsigned int lds_h1[8192];   // 32768 B = 2 bufs x [32 kblk][32 row][8k]
  __shared__ unsigned int lds_h2[8192];   // 32768 B
  __shared__ unsigned int lds_b0u[512];   // 2048 B: 1024 bf16 biases L0
  __shared__ unsigned int lds_b1u[512];   // 2048 B: L1          total 79872 B

  const int tid = threadIdx.x;
  const int wave = tid >> 6;
  const int lane = tid & 63;
  const int l15 = lane & 15;
  const int quad = lane >> 4;
  const long rowg0 = (long)blockIdx.x * 32;

  for (int i = tid; i < 8192; i += NTHREADS) { lds_h1[i] = 0u; lds_h2[i] = 0u; }
  {
    // pack biases f32 -> bf16x2 (tid in [0,512) covers all 1024 of each)
    lds_b0u[tid] = (unsigned)f2bf(b0[2 * tid]) | ((unsigned)f2bf(b0[2 * tid + 1]) << 16);
    lds_b1u[tid] = (unsigned)f2bf(b1[2 * tid]) | ((unsigned)f2bf(b1[2 * tid + 1]) << 16);
  }

  // persistent c-state: cA = state for the jt about to be processed,
  // cB = the other jt; swapped with static reg moves (round-9 trick —
  // runtime-jt indexing would demote to scratch).
  float c0A[2][4], c0B[2][4], c2A[2][4], c2B[2][4];
#pragma unroll
  for (int rt = 0; rt < 2; rt++)
#pragma unroll
    for (int r = 0; r < 4; r++) {
      c0A[rt][r] = 0.f; c0B[rt][r] = 0.f;
      c2A[rt][r] = 0.f; c2B[rt][r] = 0.f;
    }
  float fc_acc = 0.0f;

  const u32x4* lxs = (const u32x4*)lds_x;
  const u32x4* lh1 = (const u32x4*)lds_h1;
  const u32x4* lh2 = (const u32x4*)lds_h2;
  unsigned short* lh1s = (unsigned short*)lds_h1;
  unsigned short* lh2s = (unsigned short*)lds_h2;
  const u32x4* w0q = (const u32x4*)W0p;
  const u32x4* w1q = (const u32x4*)W1p;

  for (int t = 0; t < 10; t++) {
    const int rd = t & 1;        // prev-h buffer
    const int wr = rd ^ 1;       // new-h buffer

    // ---- stage x_t -> lds_x (bf16 A-layout); 32 rows x 40 quads = 1280 ----
#pragma unroll
    for (int s = 0; s < 3; s++) {
      int p = tid + s * NTHREADS;
      if (p < 1280) {
        int row = p / 40;
        int kq = p - row * 40;
        const f32x4 v = __builtin_nontemporal_load(
            (const f32x4*)(x + (rowg0 + row) * 1600 + t * 160 + kq * 4));
        unsigned lo = (unsigned)f2bf(v[0]) | ((unsigned)f2bf(v[1]) << 16);
        unsigned hi = (unsigned)f2bf(v[2]) | ((unsigned)f2bf(v[3]) << 16);
        int base = (kq >> 1) * 128 + row * 4 + (kq & 1) * 2;
        lds_x[base] = lo;
        lds_x[base + 1] = hi;
      }
    }
    __syncthreads();  // B1: x staged; h1[rd] stable from prev step

    // ======== layer 0: K=416 ([x_t | h1_prev]) ========
#pragma unroll 1
    for (int jt = 0; jt < 2; jt++) {
      const int nbb = wave * 2 + jt;
      f32x4 acc[4][2];
#pragma unroll
      for (int g = 0; g < 4; g++)
#pragma unroll
        for (int rt = 0; rt < 2; rt++) acc[g][rt] = (f32x4){0.f, 0.f, 0.f, 0.f};

      const u32x4* wp = w0q + (nbb * 52 + quad) * 64 + l15;
      const u32x4* ap = lxs + quad * 32 + l15;
      kloop32<5>(ap, wp, acc);                     // x-part: k 0..159
      ap = lh1 + rd * 1024 + quad * 32 + l15;
      kloop32<8>(ap, wp, acc);                     // h-part: k 160..415

      const int col = wave * 32 + jt * 16 + l15;
      float b_i = ldsb(lds_b0u, 0 * 256 + col);
      float b_f = ldsb(lds_b0u, 1 * 256 + col);
      float b_g = ldsb(lds_b0u, 2 * 256 + col);
      float b_o = ldsb(lds_b0u, 3 * 256 + col);
#pragma unroll
      for (int rt = 0; rt < 2; rt++)
#pragma unroll
        for (int r = 0; r < 4; r++) {
          float iv = sigm(acc[0][rt][r] + b_i);
          float fv = sigm(acc[1][rt][r] + b_f);
          float gv = tanh_fast(acc[2][rt][r] + b_g);
          float ov = sigm(acc[3][rt][r] + b_o);
          float cn = fv * c0A[rt][r] + iv * gv;
          c0A[rt][r] = cn;
          int row = rt * 16 + quad * 4 + r;
          lh1s[wr * 8192 + ((col >> 3) * 32 + row) * 8 + (col & 7)] =
              f2bf(ov * tanh_fast(cn));
        }
      // swap cA <-> cB (static register moves)
#pragma unroll
      for (int rt = 0; rt < 2; rt++)
#pragma unroll
        for (int r = 0; r < 4; r++) {
          float tmp = c0A[rt][r]; c0A[rt][r] = c0B[rt][r]; c0B[rt][r] = tmp;
        }
    }
    __syncthreads();  // B2: h1[wr] complete

    // ======== layer 1: K=512 ([h1_new | h2_prev]) ========
#pragma unroll 1
    for (int jt = 0; jt < 2; jt++) {
      const int nbb = wave * 2 + jt;
      f32x4 acc[4][2];
#pragma unroll
      for (int g = 0; g < 4; g++)
#pragma unroll
        for (int rt = 0; rt < 2; rt++) acc[g][rt] = (f32x4){0.f, 0.f, 0.f, 0.f};

      const u32x4* wp = w1q + (nbb * 64 + quad) * 64 + l15;
      const u32x4* ap = lh1 + wr * 1024 + quad * 32 + l15;
      kloop32<8>(ap, wp, acc);                     // h1_new part: k 0..255
      ap = lh2 + rd * 1024 + quad * 32 + l15;
      kloop32<8>(ap, wp, acc);                     // h2_prev part: k 256..511

      const int col = wave * 32 + jt * 16 + l15;
      float b_i = ldsb(lds_b1u, 0 * 256 + col);
      float b_f = ldsb(lds_b1u, 1 * 256 + col);
      float b_g = ldsb(lds_b1u, 2 * 256 + col);
      float b_o = ldsb(lds_b1u, 3 * 256 + col);
#pragma unroll
      for (int rt = 0; rt < 2; rt++)
#pragma unroll
        for (int r = 0; r < 4; r++) {
          float iv = sigm(acc[0][rt][r] + b_i);
          float fv = sigm(acc[1][rt][r] + b_f);
          float gv = tanh_fast(acc[2][rt][r] + b_g);
          float ov = sigm(acc[3][rt][r] + b_o);
          float cn = fv * c2A[rt][r] + iv * gv;
          c2A[rt][r] = cn;
          int row = rt * 16 + quad * 4 + r;
          lh2s[wr * 8192 + ((col >> 3) * 32 + row) * 8 + (col & 7)] =
              f2bf(ov * tanh_fast(cn));
        }
      // swap cA <-> cB
#pragma unroll
      for (int rt = 0; rt < 2; rt++)
#pragma unroll
        for (int r = 0; r < 4; r++) {
          float tmp = c2A[rt][r]; c2A[rt][r] = c2B[rt][r]; c2B[rt][r] = tmp;
        }
    }
    __syncthreads();  // B3: h2[wr] complete

    // ---- FC partial: logit += W_fc[t*256 + j] * h2_new[row][j] ----
    {
      int row = tid >> 4;          // 32 rows
      int slot = tid & 15;         // 16 col-slots x 16 cols
      float s = 0.f;
#pragma unroll
      for (int kb = 0; kb < 2; kb++) {
        u32x4 hv = lh2[wr * 1024 + (slot * 2 + kb) * 32 + row];
        const f32x4 wA = *(const f32x4*)(Wfc + t * 256 + slot * 16 + kb * 8);
        const f32x4 wB = *(const f32x4*)(Wfc + t * 256 + slot * 16 + kb * 8 + 4);
#pragma unroll
        for (int e = 0; e < 2; e++) {
          unsigned u = hv[e];
          s += bf2f((unsigned short)(u & 0xffffu)) * wA[2 * e];
          s += bf2f((unsigned short)(u >> 16)) * wA[2 * e + 1];
        }
#pragma unroll
        for (int e = 0; e < 2; e++) {
          unsigned u = hv[2 + e];
          s += bf2f((unsigned short)(u & 0xffffu)) * wB[2 * e];
          s += bf2f((unsigned short)(u >> 16)) * wB[2 * e + 1];
        }
      }
      fc_acc += s;
    }
    // no barrier: next staging touches lds_x only; dbuf protects h regions.
  }

  // final FC reduction — reuse lds_x as scratch (free after last L0)
  float* lds_redp = (float*)lds_x;
  lds_redp[tid] = fc_acc;          // [row(32)][slot(16)]
  __syncthreads();
  if (tid < 32) {
    float s = 0.f;
#pragma unroll
    for (int e = 0; e < 16; e++) s += lds_redp[tid * 16 + e];
    out[rowg0 + tid] = sigm(s + bfc[0]);
  }
}

extern "C" void kernel_launch(void* const* d_in, const int* in_sizes, int n_in,
                              void* d_out, int out_size, void* d_ws, size_t ws_size,
                              hipStream_t stream) {
  const float* x    = (const float*)d_in[0];
  const float* Wih0 = (const float*)d_in[1];
  const float* Whh0 = (const float*)d_in[2];
  const float* bih0 = (const float*)d_in[3];
  const float* bhh0 = (const float*)d_in[4];
  const float* Wih1 = (const float*)d_in[5];
  const float* Whh1 = (const float*)d_in[6];
  const float* bih1 = (const float*)d_in[7];
  const float* bhh1 = (const float*)d_in[8];
  const float* Wfc  = (const float*)d_in[9];
  const float* bfc  = (const float*)d_in[10];
  float* out = (float*)d_out;

  unsigned short* W0p = (unsigned short*)d_ws;         // 425984 bf16
  unsigned short* W1p = W0p + 16 * 52 * 4 * 128;       // 524288 bf16
  float* b0 = (float*)(W1p + 16 * 64 * 4 * 128);       // 1024 f32
  float* b1 = b0 + 1024;                               // 1024 f32

  const int total = 16 * 52 * 4 * 128 + 16 * 64 * 4 * 128 + 2048;
  pack_weights<<<(total + 255) / 256, 256, 0, stream>>>(
      Wih0, Whh0, bih0, bhh0, Wih1, Whh1, bih1, bhh1, W0p, W1p, b0, b1);
  lstm_fused<<<512, NTHREADS, 0, stream>>>(x, W0p, W1p, b0, b1, Wfc, bfc, out);
}